// Round 1
// baseline (549.175 us; speedup 1.0000x reference)
//
#include <hip/hip_runtime.h>

// MLPPredictor: score[e,c] = bias[c] + sum_k concat(h[src[e]], h[dst[e]])[k] * W[c][k]
// N_NODES=100000, E=6.4M, D=5, C=16. fp32 in/out, int32 indices.
//
// v2 theory (v1 = 570.7us was gather-transaction + latency bound, ~6x off the
// ~80us write-stream roofline):
//  * h padded to 8 floats/row (32B, line-aligned) in workspace -> a row is two
//    aligned float4s in ONE 64B line (v1: 5 scalar dword instrs re-requesting it).
//  * 4 threads/edge (quad): lane j loads ONE float4 (0:u.lo 1:u.hi 2:v.lo 3:v.hi)
//    -> ONE gather instruction per wave-iter, ~2 line-transactions/edge (was ~12).
//    9 quad_perm DPP exchanges broadcast the 10 useful floats to the quad
//    (VALU pipe; __shfl_xor would go to ds_swizzle/LDS pipe).
//  * non-temporal idx loads + output stores: 410MB store stream must not evict
//    L2-resident h8 that the random gathers hit.
//  * 2-item unroll + next-pair index prefetch: hide ~900cy HBM index latency.
// Output mapping unchanged from v1: thread g -> edge g>>2, class-quad g&3,
// one float4 store at out+g*4 (perfectly coalesced).

typedef float f4v __attribute__((ext_vector_type(4)));

constexpr int C = 16;
constexpr int TWO_D = 10;
constexpr int D = 5;
constexpr int N_NODES = 100000;  // fixed problem size; indices < N_NODES

// quad_perm DPP: xor1 = perm[1,0,3,2] = 0xB1 ; xor2 = perm[2,3,0,1] = 0x4E
template <int CTRL>
__device__ __forceinline__ float qperm(float x) {
    return __int_as_float(
        __builtin_amdgcn_mov_dpp(__float_as_int(x), CTRL, 0xF, 0xF, true));
}

__global__ __launch_bounds__(256) void pad_h_kernel(
    const float* __restrict__ h, float* __restrict__ h8, int total8)
{
    for (int i = blockIdx.x * blockDim.x + threadIdx.x; i < total8;
         i += gridDim.x * blockDim.x) {
        const int row = i >> 3, k = i & 7;
        h8[i] = (k < D) ? h[row * D + k] : 0.0f;
    }
}

__global__ __launch_bounds__(256) void edge_mlp_v2(
    const float* __restrict__ h8,   // [N_NODES][8] padded rows
    const int* __restrict__ src,
    const int* __restrict__ dst,
    const float* __restrict__ Ww,   // [C][2D]
    const float* __restrict__ Wb,   // [C]
    float* __restrict__ out,        // [E][C]
    int totalItems)                 // E*4
{
    __shared__ float sW[C * TWO_D + C];
    for (int i = threadIdx.x; i < C * TWO_D + C; i += blockDim.x)
        sW[i] = (i < C * TWO_D) ? Ww[i] : Wb[i - C * TWO_D];
    __syncthreads();

    const int tid0 = blockIdx.x * blockDim.x + threadIdx.x;
    const int q = tid0 & 3;            // invariant: stride % 4 == 0
    const bool hiHalf = (q & 1) != 0;  // loads elems 4..7 of its row
    const bool isV = (q >= 2);         // loads the dst row

    // register-resident W tile for my 4 classes
    float w[4][TWO_D], bias[4];
#pragma unroll
    for (int j = 0; j < 4; ++j) {
        const int c = q * 4 + j;
#pragma unroll
        for (int k = 0; k < TWO_D; ++k) w[j][k] = sW[c * TWO_D + k];
        bias[j] = sW[C * TWO_D + c];
    }

    const int stride = gridDim.x * blockDim.x;
    const int stride2 = stride * 2;
    const int TImax = totalItems - 1;

    auto clampE = [&](int g) { return (g < TImax ? g : TImax) >> 2; };

    // compute + (guarded) store for one item, given my quad's float4
    auto body = [&](const f4v gv, int gout, bool doStore) {
        // round 1 (xor 1): get the other half of MY row
        f4v o1;
        o1[0] = qperm<0xB1>(gv[0]); o1[1] = qperm<0xB1>(gv[1]);
        o1[2] = qperm<0xB1>(gv[2]); o1[3] = qperm<0xB1>(gv[3]);
        const f4v mlo = hiHalf ? o1 : gv;        // my row elems 0..3
        const float m4 = hiHalf ? gv[0] : o1[0]; // my row elem 4
        // round 2 (xor 2): swap u-row <-> v-row between half-quads
        f4v olo;
        olo[0] = qperm<0x4E>(mlo[0]); olo[1] = qperm<0x4E>(mlo[1]);
        olo[2] = qperm<0x4E>(mlo[2]); olo[3] = qperm<0x4E>(mlo[3]);
        const float o4 = qperm<0x4E>(m4);

        const float u0 = isV ? olo[0] : mlo[0];
        const float u1 = isV ? olo[1] : mlo[1];
        const float u2 = isV ? olo[2] : mlo[2];
        const float u3 = isV ? olo[3] : mlo[3];
        const float u4 = isV ? o4     : m4;
        const float v0 = isV ? mlo[0] : olo[0];
        const float v1 = isV ? mlo[1] : olo[1];
        const float v2 = isV ? mlo[2] : olo[2];
        const float v3 = isV ? mlo[3] : olo[3];
        const float v4 = isV ? m4     : o4;

        f4v r;
#pragma unroll
        for (int j = 0; j < 4; ++j) {
            float a = bias[j];
            a += u0 * w[j][0] + u1 * w[j][1] + u2 * w[j][2] + u3 * w[j][3] + u4 * w[j][4];
            a += v0 * w[j][5] + v1 * w[j][6] + v2 * w[j][7] + v3 * w[j][8] + v4 * w[j][9];
            r[j] = a;
        }
        if (doStore)
            __builtin_nontemporal_store(r, reinterpret_cast<f4v*>(out + (size_t)gout * 4));
    };

    // prologue: indices for the first pair
    int g = tid0;
    int eA = clampE(g), eB = clampE(g + stride);
    int sA = __builtin_nontemporal_load(src + eA);
    int dA = __builtin_nontemporal_load(dst + eA);
    int sB = __builtin_nontemporal_load(src + eB);
    int dB = __builtin_nontemporal_load(dst + eB);

    for (; g < totalItems; g += stride2) {
        // issue both gathers for the current pair (indices prefetched last iter)
        const int rA = isV ? dA : sA;
        const int rB = isV ? dB : sB;
        const f4v gvA = *reinterpret_cast<const f4v*>(h8 + (size_t)rA * 8 + (hiHalf ? 4 : 0));
        const f4v gvB = *reinterpret_cast<const f4v*>(h8 + (size_t)rB * 8 + (hiHalf ? 4 : 0));

        // prefetch next pair's indices (clamped -> always safe, no divergence)
        const int gn = g + stride2;
        eA = clampE(gn); eB = clampE(gn + stride);
        sA = __builtin_nontemporal_load(src + eA);
        dA = __builtin_nontemporal_load(dst + eA);
        sB = __builtin_nontemporal_load(src + eB);
        dB = __builtin_nontemporal_load(dst + eB);

        body(gvA, g, true);
        body(gvB, g + stride, (g + stride) < totalItems);
    }
}

// v1 fallback (identical to the previously verified kernel) for the case the
// harness gives us no / too little workspace for the padded h copy.
__global__ __launch_bounds__(256) void edge_mlp_v1(
    const float* __restrict__ h,
    const int* __restrict__ src,
    const int* __restrict__ dst,
    const float* __restrict__ Ww,
    const float* __restrict__ Wb,
    float* __restrict__ out,
    int totalItems)
{
    __shared__ float sW[C * TWO_D + C];
    for (int i = threadIdx.x; i < C * TWO_D + C; i += blockDim.x)
        sW[i] = (i < C * TWO_D) ? Ww[i] : Wb[i - C * TWO_D];
    __syncthreads();

    const int tid0 = blockIdx.x * blockDim.x + threadIdx.x;
    const int q = tid0 & 3;
    float w[4][TWO_D], bias[4];
#pragma unroll
    for (int j = 0; j < 4; ++j) {
        const int c = q * 4 + j;
#pragma unroll
        for (int k = 0; k < TWO_D; ++k) w[j][k] = sW[c * TWO_D + k];
        bias[j] = sW[C * TWO_D + c];
    }

    const int stride = gridDim.x * blockDim.x;
    for (int g = tid0; g < totalItems; g += stride) {
        const int e = g >> 2;
        const int s = src[e];
        const int d = dst[e];
        const float* pu = h + s * 5;
        const float* pv = h + d * 5;
        const float u0 = pu[0], u1 = pu[1], u2 = pu[2], u3 = pu[3], u4 = pu[4];
        const float v0 = pv[0], v1 = pv[1], v2 = pv[2], v3 = pv[3], v4 = pv[4];
        float4 r;
        float* rp = &r.x;
#pragma unroll
        for (int j = 0; j < 4; ++j) {
            float a = bias[j];
            a += u0 * w[j][0] + u1 * w[j][1] + u2 * w[j][2] + u3 * w[j][3] + u4 * w[j][4];
            a += v0 * w[j][5] + v1 * w[j][6] + v2 * w[j][7] + v3 * w[j][8] + v4 * w[j][9];
            rp[j] = a;
        }
        *reinterpret_cast<float4*>(out + (size_t)g * 4) = r;
    }
}

extern "C" void kernel_launch(void* const* d_in, const int* in_sizes, int n_in,
                              void* d_out, int out_size, void* d_ws, size_t ws_size,
                              hipStream_t stream) {
    const float* h   = (const float*)d_in[0];   // [100000, 5]
    const int*   src = (const int*)d_in[1];     // [E]
    const int*   dst = (const int*)d_in[2];     // [E]
    const float* Ww  = (const float*)d_in[3];   // [16, 10]
    const float* Wb  = (const float*)d_in[4];   // [16]
    float* out = (float*)d_out;                 // [E, 16]

    const int E = in_sizes[1];
    const int totalItems = E * 4;               // 25.6M, fits int

    const size_t needWs = (size_t)N_NODES * 8 * sizeof(float);  // 3.2 MB
    if (d_ws != nullptr && ws_size >= needWs) {
        float* h8 = (float*)d_ws;
        pad_h_kernel<<<1024, 256, 0, stream>>>(h, h8, N_NODES * 8);
        edge_mlp_v2<<<4096, 256, 0, stream>>>(h8, src, dst, Ww, Wb, out, totalItems);
    } else {
        edge_mlp_v1<<<4096, 256, 0, stream>>>(h, src, dst, Ww, Wb, out, totalItems);
    }
}